// Round 1
// baseline (491.442 us; speedup 1.0000x reference)
//
#include <hip/hip_runtime.h>
#include <hip/hip_bf16.h>

// Problem constants (from setup_inputs): K=64 clouds, d=320 feats, N=2048 pts,
// M=128 clusters, S=K*M=8192 segments.
#define KC 64
#define DD 320
#define NP 2048
#define MC 128
#define SS (KC * MC)
#define CHUNK 32              // features per block in kernel 1
#define NCHUNK (DD / CHUNK)   // 10
#define EPSV 1e-12f

// ---------------------------------------------------------------------------
// Kernel 1: per-(cloud, feature-chunk) segment reduction via LDS histogram.
// Each block exclusively owns rows [k*M, k*M+M) x cols [chunk*32, chunk*32+32)
// of cluster_means, so no global atomics are needed.
// ---------------------------------------------------------------------------
__global__ __launch_bounds__(256) void seg_reduce_kernel(
    const float* __restrict__ feat,     // (K, d, N)
    const float* __restrict__ label,    // (K, N)
    const int* __restrict__ clab,       // (K, N)
    float* __restrict__ means_out,      // (S, d)
    float* __restrict__ counts_ws,      // (S,)
    float* __restrict__ lblsum_ws)      // (S,)
{
    const int k = blockIdx.x;
    const int chunk = blockIdx.y;
    const int tid = threadIdx.x;

    __shared__ int   s_cl[NP];            // 8 KB
    __shared__ float s_acc[CHUNK][MC + 1]; // padded: write-out read is conflict-free
    __shared__ int   s_cnt[MC];
    __shared__ float s_lbl[MC];

    // stage cluster ids
    for (int n = tid; n < NP; n += 256) s_cl[n] = clab[k * NP + n];
    for (int i = tid; i < CHUNK * (MC + 1); i += 256) (&s_acc[0][0])[i] = 0.f;
    if (tid < MC) { s_cnt[tid] = 0; s_lbl[tid] = 0.f; }
    __syncthreads();

    // each thread owns points {tid*4..tid*4+3} and {+1024..}; ids fixed across features
    int cl0[4], cl1[4];
#pragma unroll
    for (int q = 0; q < 4; ++q) {
        cl0[q] = s_cl[tid * 4 + q];
        cl1[q] = s_cl[tid * 4 + 1024 + q];
    }

    // counts (every block needs denom); labels only once (chunk 0)
#pragma unroll
    for (int q = 0; q < 4; ++q) {
        atomicAdd(&s_cnt[cl0[q]], 1);
        atomicAdd(&s_cnt[cl1[q]], 1);
    }
    if (chunk == 0) {
        const float4 la = reinterpret_cast<const float4*>(label + (size_t)k * NP)[tid];
        const float4 lb = reinterpret_cast<const float4*>(label + (size_t)k * NP)[tid + 256];
        unsafeAtomicAdd(&s_lbl[cl0[0]], la.x);
        unsafeAtomicAdd(&s_lbl[cl0[1]], la.y);
        unsafeAtomicAdd(&s_lbl[cl0[2]], la.z);
        unsafeAtomicAdd(&s_lbl[cl0[3]], la.w);
        unsafeAtomicAdd(&s_lbl[cl1[0]], lb.x);
        unsafeAtomicAdd(&s_lbl[cl1[1]], lb.y);
        unsafeAtomicAdd(&s_lbl[cl1[2]], lb.z);
        unsafeAtomicAdd(&s_lbl[cl1[3]], lb.w);
    }

    // feature accumulation: 32 features x 2048 points per block
    const float* fbase = feat + (size_t)k * DD * NP + (size_t)chunk * CHUNK * NP;
    for (int j = 0; j < CHUNK; ++j) {
        const float4* f4 = reinterpret_cast<const float4*>(fbase + (size_t)j * NP);
        const float4 a = f4[tid];
        const float4 b = f4[tid + 256];
        float* accj = &s_acc[j][0];
        unsafeAtomicAdd(&accj[cl0[0]], a.x);
        unsafeAtomicAdd(&accj[cl0[1]], a.y);
        unsafeAtomicAdd(&accj[cl0[2]], a.z);
        unsafeAtomicAdd(&accj[cl0[3]], a.w);
        unsafeAtomicAdd(&accj[cl1[0]], b.x);
        unsafeAtomicAdd(&accj[cl1[1]], b.y);
        unsafeAtomicAdd(&accj[cl1[2]], b.z);
        unsafeAtomicAdd(&accj[cl1[3]], b.w);
    }
    __syncthreads();

    // write means: lanes 0..31 -> j 0..31 of one cluster row (128B contiguous)
    for (int i = tid; i < CHUNK * MC; i += 256) {
        const int j = i & 31;
        const int m = i >> 5;
        const float denom = fmaxf((float)s_cnt[m], 1.0f);
        means_out[(size_t)(k * MC + m) * DD + chunk * CHUNK + j] = s_acc[j][m] / denom;
    }
    if (chunk == 0) {
        for (int m = tid; m < MC; m += 256) {
            counts_ws[k * MC + m] = (float)s_cnt[m];
            lblsum_ws[k * MC + m] = s_lbl[m];
        }
    }
}

// ---------------------------------------------------------------------------
// Kernel 2: per-segment stats (single block): cls_mask, weight, n_valid
// ---------------------------------------------------------------------------
__global__ __launch_bounds__(256) void stats_kernel(
    const float* __restrict__ counts,
    const float* __restrict__ lblsum,
    float* __restrict__ cls,
    float* __restrict__ weight,
    float* __restrict__ nvalid_out)
{
    __shared__ float red_max[256];
    __shared__ float red_sum[256];
    const int tid = threadIdx.x;
    float lmax = 0.f, lsum = 0.f;
    for (int s = tid; s < SS; s += 256) {
        const float c = counts[s];
        const float lm = lblsum[s] / fmaxf(c, 1.f);
        const bool is_cls = (lm > 0.5f) && (c > 0.f);
        cls[s] = is_cls ? 1.f : 0.f;
        const float sz = is_cls ? c : 0.f;
        lmax = fmaxf(lmax, sz);
        lsum += is_cls ? 1.f : 0.f;
    }
    red_max[tid] = lmax;
    red_sum[tid] = lsum;
    __syncthreads();
    for (int off = 128; off > 0; off >>= 1) {
        if (tid < off) {
            red_max[tid] = fmaxf(red_max[tid], red_max[tid + off]);
            red_sum[tid] += red_sum[tid + off];
        }
        __syncthreads();
    }
    const float mx = fmaxf(red_max[0], 1.f);
    for (int s = tid; s < SS; s += 256) {
        weight[s] = (cls[s] * counts[s]) / mx;
    }
    if (tid == 0) nvalid_out[0] = fmaxf(red_sum[0], 1.f);
}

// ---------------------------------------------------------------------------
// Kernel 3: per-segment norm + masked inverse norm; per-block partial of
// v = sum_s weight[s] * fn[s, :].  One wave per 16 segments, 4 waves/block.
// ---------------------------------------------------------------------------
__global__ __launch_bounds__(256) void norm_v_kernel(
    const float* __restrict__ means,    // (S, d)
    const float* __restrict__ cls,
    const float* __restrict__ weight,
    float* __restrict__ rw,             // (S,)  masked 1/norm
    float* __restrict__ vpart)          // (128, d)
{
    const int wid = threadIdx.x >> 6;
    const int lane = threadIdx.x & 63;
    const int seg0 = blockIdx.x * 64 + wid * 16;

    double vacc[5] = {0, 0, 0, 0, 0};
    for (int i = 0; i < 16; ++i) {
        const int s = seg0 + i;
        const float* row = means + (size_t)s * DD;
        float val[5];
        float ss = 0.f;
#pragma unroll
        for (int r = 0; r < 5; ++r) {
            val[r] = row[r * 64 + lane];
            ss = fmaf(val[r], val[r], ss);
        }
#pragma unroll
        for (int off = 32; off > 0; off >>= 1) ss += __shfl_xor(ss, off, 64);
        const float norm = sqrtf(ss);
        const float inv = 1.f / fmaxf(norm, EPSV);
        const float rwv = cls[s] * inv;
        if (lane == 0) rw[s] = rwv;
        const float coef = weight[s] * rwv;
#pragma unroll
        for (int r = 0; r < 5; ++r) vacc[r] += (double)(coef * val[r]);
    }

    __shared__ float vtmp[4][DD];
#pragma unroll
    for (int r = 0; r < 5; ++r) vtmp[wid][r * 64 + lane] = (float)vacc[r];
    __syncthreads();
    for (int j = threadIdx.x; j < DD; j += 256) {
        vpart[(size_t)blockIdx.x * DD + j] =
            vtmp[0][j] + vtmp[1][j] + vtmp[2][j] + vtmp[3][j];
    }
}

// Kernel 3b: reduce 128 partial v's -> v (320 floats). launch <<<5, 64>>>
__global__ void v_reduce_kernel(const float* __restrict__ vpart,
                                float* __restrict__ v)
{
    const int j = blockIdx.x * 64 + threadIdx.x;
    if (j < DD) {
        float acc = 0.f;
        for (int b = 0; b < 128; ++b) acc += vpart[(size_t)b * DD + j];
        v[j] = acc;
    }
}

// ---------------------------------------------------------------------------
// Kernel 4: sim_score[s] = rw[s] * dot(means[s], v); per-block partial sum of
// sim (non-class rows contribute 0 since rw=0).
// ---------------------------------------------------------------------------
__global__ __launch_bounds__(256) void sim_kernel(
    const float* __restrict__ means,
    const float* __restrict__ rw,
    const float* __restrict__ v,
    float* __restrict__ sim_out,
    float* __restrict__ simpart)       // (128,)
{
    const int wid = threadIdx.x >> 6;
    const int lane = threadIdx.x & 63;
    const int seg0 = blockIdx.x * 64 + wid * 16;

    float vreg[5];
#pragma unroll
    for (int r = 0; r < 5; ++r) vreg[r] = v[r * 64 + lane];

    float lsum = 0.f;
    for (int i = 0; i < 16; ++i) {
        const int s = seg0 + i;
        const float* row = means + (size_t)s * DD;
        float dot = 0.f;
#pragma unroll
        for (int r = 0; r < 5; ++r) dot = fmaf(row[r * 64 + lane], vreg[r], dot);
#pragma unroll
        for (int off = 32; off > 0; off >>= 1) dot += __shfl_xor(dot, off, 64);
        const float sim = rw[s] * dot;
        if (lane == 0) {
            sim_out[s] = sim;
            lsum += sim;
        }
    }
    __shared__ float stmp[4];
    if (lane == 0) stmp[wid] = lsum;
    __syncthreads();
    if (threadIdx.x == 0)
        simpart[blockIdx.x] = stmp[0] + stmp[1] + stmp[2] + stmp[3];
}

// ---------------------------------------------------------------------------
// Kernel 5: mean_score + clean_mask (single block)
// ---------------------------------------------------------------------------
__global__ __launch_bounds__(256) void clean_kernel(
    const float* __restrict__ sim,
    const float* __restrict__ cls,
    const float* __restrict__ simpart,
    const float* __restrict__ nvalid,
    float* __restrict__ clean_out)
{
    __shared__ float red[256];
    __shared__ float mean_s;
    const int tid = threadIdx.x;
    red[tid] = (tid < 128) ? simpart[tid] : 0.f;
    __syncthreads();
    for (int off = 128; off > 0; off >>= 1) {
        if (tid < off) red[tid] += red[tid + off];
        __syncthreads();
    }
    if (tid == 0) mean_s = red[0] / nvalid[0];
    __syncthreads();
    const float mean = mean_s;
    for (int s = tid; s < SS; s += 256) {
        clean_out[s] = ((sim[s] > mean) && (cls[s] != 0.f)) ? 1.f : 0.f;
    }
}

extern "C" void kernel_launch(void* const* d_in, const int* in_sizes, int n_in,
                              void* d_out, int out_size, void* d_ws, size_t ws_size,
                              hipStream_t stream) {
    const float* feat  = (const float*)d_in[0];   // (K, d, N) f32
    const float* label = (const float*)d_in[1];   // (K, N)    f32
    const int*   clab  = (const int*)d_in[2];     // (K, N)    i32

    float* out       = (float*)d_out;
    float* means_out = out;                        // S*d
    float* sim_out   = out + (size_t)SS * DD;      // S
    float* clean_out = sim_out + SS;               // S

    float* ws      = (float*)d_ws;
    float* counts  = ws;                 // S
    float* lblsum  = ws + SS;            // S
    float* cls     = ws + 2 * SS;        // S
    float* weight  = ws + 3 * SS;        // S
    float* rw      = ws + 4 * SS;        // S
    float* vpart   = ws + 5 * SS;        // 128*320
    float* v       = vpart + 128 * DD;   // 320
    float* simpart = v + DD;             // 128
    float* nvalid  = simpart + 128;      // 1

    dim3 g1(KC, NCHUNK);
    seg_reduce_kernel<<<g1, 256, 0, stream>>>(feat, label, clab, means_out,
                                              counts, lblsum);
    stats_kernel<<<1, 256, 0, stream>>>(counts, lblsum, cls, weight, nvalid);
    norm_v_kernel<<<128, 256, 0, stream>>>(means_out, cls, weight, rw, vpart);
    v_reduce_kernel<<<5, 64, 0, stream>>>(vpart, v);
    sim_kernel<<<128, 256, 0, stream>>>(means_out, rw, v, sim_out, simpart);
    clean_kernel<<<1, 256, 0, stream>>>(sim_out, cls, simpart, nvalid, clean_out);
}

// Round 3
// 288.878 us; speedup vs baseline: 1.7012x; 1.7012x over previous
//
#include <hip/hip_runtime.h>
#include <hip/hip_bf16.h>

// K=64 clouds, d=320 feats, N=2048 pts, M=128 clusters, S=8192 segments.
#define KC 64
#define DD 320
#define NP 2048
#define MC 128
#define SS (KC * MC)
#define EPSV 1e-12f

// means kernel geometry
#define CHUNKF 20            // features per block
#define NCHUNKF 16           // 320 / 20
#define GFEAT 4              // features staged per group
#define NGROUP 5             // CHUNKF / GFEAT
#define TILEW 2176           // 2048 + 2048/16 (skewed width)

// ---------------------------------------------------------------------------
// Kernel A: per-cloud counting sort + cluster stats.
// Histogram via returning LDS atomics (rank), scan -> starts, emit skewed
// sorted position per point. Also computes cls/sizes and global max/nvalid.
// ---------------------------------------------------------------------------
__global__ __launch_bounds__(256) void sortstats_kernel(
    const float* __restrict__ label,    // (K, N)
    const int* __restrict__ clab,       // (K, N)
    unsigned short* __restrict__ spos_ws,  // (K, N) skewed sorted pos
    int* __restrict__ starts_ws,        // (K, 129)
    float* __restrict__ cls_ws,         // (S,)
    float* __restrict__ sizes_ws,       // (S,)
    unsigned* __restrict__ maxbits,     // zeroed; atomicMax of float bits
    float* __restrict__ nvalid)         // zeroed; atomicAdd
{
    const int k = blockIdx.x;
    const int tid = threadIdx.x;

    __shared__ int   s_cnt[MC];
    __shared__ float s_lbl[MC];
    __shared__ int   s_scan[MC + 1];
    __shared__ float s_red[256];

    if (tid < MC) { s_cnt[tid] = 0; s_lbl[tid] = 0.f; }
    __syncthreads();

    int id[8], rk[8];
#pragma unroll
    for (int i = 0; i < 8; ++i) {
        const int p = i * 256 + tid;
        id[i] = clab[k * NP + p];
        rk[i] = atomicAdd(&s_cnt[id[i]], 1);
        unsafeAtomicAdd(&s_lbl[id[i]], label[k * NP + p]);
    }
    __syncthreads();

    // inclusive scan over counts -> starts: s_scan[m] = sum cnt[0..m-1]
    if (tid < MC) s_scan[tid + 1] = s_cnt[tid];
    if (tid == 0) s_scan[0] = 0;
    __syncthreads();
    for (int off = 1; off < MC; off <<= 1) {
        int v = 0;
        if (tid < MC && (tid + 1) > off) v = s_scan[tid + 1 - off];
        __syncthreads();
        if (tid < MC) s_scan[tid + 1] += v;
        __syncthreads();
    }

    // per-cluster stats
    float localmax = 0.f, localval = 0.f;
    if (tid < MC) {
        const int c = s_cnt[tid];
        const float lm = s_lbl[tid] / fmaxf((float)c, 1.f);
        const bool is = (lm > 0.5f) && (c > 0);
        const float sz = is ? (float)c : 0.f;
        cls_ws[k * MC + tid] = is ? 1.f : 0.f;
        sizes_ws[k * MC + tid] = sz;
        localmax = sz;
        localval = is ? 1.f : 0.f;
    }
    s_red[tid] = localmax;
    __syncthreads();
    for (int off = 128; off > 0; off >>= 1) {
        if (tid < off) s_red[tid] = fmaxf(s_red[tid], s_red[tid + off]);
        __syncthreads();
    }
    if (tid == 0) atomicMax(maxbits, __float_as_uint(s_red[0]));
    __syncthreads();
    s_red[tid] = localval;
    __syncthreads();
    for (int off = 128; off > 0; off >>= 1) {
        if (tid < off) s_red[tid] += s_red[tid + off];
        __syncthreads();
    }
    if (tid == 0) unsafeAtomicAdd(nvalid, s_red[0]);

    // outputs: starts + skewed sorted positions
    for (int i = tid; i < MC + 1; i += 256) starts_ws[k * (MC + 1) + i] = s_scan[i];
#pragma unroll
    for (int i = 0; i < 8; ++i) {
        const int p = i * 256 + tid;
        const int sp0 = s_scan[id[i]] + rk[i];
        spos_ws[k * NP + p] = (unsigned short)(sp0 + (sp0 >> 4));
    }
}

// ---------------------------------------------------------------------------
// Kernel C: segment means. Block = (cloud k, 20-feature chunk). Double-buffered:
// coalesced float4 loads -> plain ds_write scatter to skewed sorted positions ->
// per-(cluster, feature) contiguous segment sum from LDS into registers.
// No atomics. Skew makes the segment reads bank-conflict-free.
// ---------------------------------------------------------------------------
__global__ __launch_bounds__(512) void means_kernel(
    const float* __restrict__ feat,           // (K, d, N)
    const unsigned short* __restrict__ spos_ws,
    const int* __restrict__ starts_ws,
    float* __restrict__ means_out)            // (S, d)
{
    const int k = blockIdx.x;
    const int chunk = blockIdx.y;
    const int tid = threadIdx.x;

    __shared__ float s_tile[2][GFEAT][TILEW];   // 69.6 KB
    __shared__ unsigned short s_sp[NP];         // 4 KB
    __shared__ int s_starts[MC + 1];

    // stage skewed positions + starts
    {
        const unsigned* spg = (const unsigned*)(spos_ws + (size_t)k * NP);
        for (int i = tid; i < NP / 2; i += 512) ((unsigned*)s_sp)[i] = spg[i];
        if (tid < MC + 1) s_starts[tid] = starts_ws[k * (MC + 1) + tid];
    }
    __syncthreads();

    const int m = tid & 127;   // cluster for accumulate; column group for staging
    const int r = tid >> 7;    // 0..3: tile row (feature within group)

    // my 16 staged points: float4 indices m + 128*q  (coalesced loads)
    unsigned short sp[16];
#pragma unroll
    for (int q = 0; q < 4; ++q) {
        const int p0 = (m + 128 * q) * 4;
#pragma unroll
        for (int e = 0; e < 4; ++e) sp[4 * q + e] = s_sp[p0 + e];
    }

    const int st = s_starts[m];
    const int en = s_starts[m + 1];
    const float invd = 1.0f / fmaxf((float)(en - st), 1.0f);

    const float* fb = feat + (size_t)k * DD * NP + (size_t)chunk * CHUNKF * NP;
    float regsum[NGROUP];
    float4 ld[4];

    // prologue: load + stage group 0
    {
        const float4* src = (const float4*)(fb + (size_t)r * NP);
#pragma unroll
        for (int q = 0; q < 4; ++q) ld[q] = src[m + 128 * q];
#pragma unroll
        for (int q = 0; q < 4; ++q) {
            s_tile[0][r][sp[4 * q + 0]] = ld[q].x;
            s_tile[0][r][sp[4 * q + 1]] = ld[q].y;
            s_tile[0][r][sp[4 * q + 2]] = ld[q].z;
            s_tile[0][r][sp[4 * q + 3]] = ld[q].w;
        }
    }
    __syncthreads();

#pragma unroll
    for (int g = 0; g < NGROUP; ++g) {
        const int cur = g & 1;
        // issue next group's loads early (hide HBM latency under accumulate)
        if (g + 1 < NGROUP) {
            const float4* src = (const float4*)(fb + (size_t)((g + 1) * GFEAT + r) * NP);
#pragma unroll
            for (int q = 0; q < 4; ++q) ld[q] = src[m + 128 * q];
        }
        // contiguous segment sum for (cluster m, feature g*4+r)
        float acc = 0.f;
        for (int qq = st; qq < en; ++qq) {
            acc += s_tile[cur][r][qq + (qq >> 4)];
        }
        regsum[g] = acc;
        // scatter-stage next group into the other buffer
        if (g + 1 < NGROUP) {
#pragma unroll
            for (int q = 0; q < 4; ++q) {
                s_tile[cur ^ 1][r][sp[4 * q + 0]] = ld[q].x;
                s_tile[cur ^ 1][r][sp[4 * q + 1]] = ld[q].y;
                s_tile[cur ^ 1][r][sp[4 * q + 2]] = ld[q].z;
                s_tile[cur ^ 1][r][sp[4 * q + 3]] = ld[q].w;
            }
        }
        __syncthreads();
    }

    // write means: thread (m, r) owns features g*4+r of cluster row m
    float* mrow = means_out + (size_t)(k * MC + m) * DD + chunk * CHUNKF;
#pragma unroll
    for (int g = 0; g < NGROUP; ++g) mrow[g * GFEAT + r] = regsum[g] * invd;
}

// ---------------------------------------------------------------------------
// Kernel 3: per-segment norm + masked 1/norm; v = sum_s weight[s]*fn[s,:]
// accumulated via global f32 atomics (v pre-zeroed).
// ---------------------------------------------------------------------------
__global__ __launch_bounds__(256) void norm_v_kernel(
    const float* __restrict__ means,
    const float* __restrict__ cls,
    const float* __restrict__ sizes,
    const unsigned* __restrict__ maxbits,
    float* __restrict__ rw,
    float* __restrict__ v)
{
    const int wid = threadIdx.x >> 6;
    const int lane = threadIdx.x & 63;
    const int seg0 = blockIdx.x * 64 + wid * 16;
    const float rmx = 1.0f / fmaxf(__uint_as_float(*maxbits), 1.0f);

    float vacc[5] = {0, 0, 0, 0, 0};
    for (int i = 0; i < 16; ++i) {
        const int s = seg0 + i;
        const float* row = means + (size_t)s * DD;
        float val[5];
        float ssum = 0.f;
#pragma unroll
        for (int r = 0; r < 5; ++r) {
            val[r] = row[r * 64 + lane];
            ssum = fmaf(val[r], val[r], ssum);
        }
#pragma unroll
        for (int off = 32; off > 0; off >>= 1) ssum += __shfl_xor(ssum, off, 64);
        const float inv = 1.f / fmaxf(sqrtf(ssum), EPSV);
        const float rwv = cls[s] * inv;
        if (lane == 0) rw[s] = rwv;
        const float coef = sizes[s] * rmx * rwv;
#pragma unroll
        for (int r = 0; r < 5; ++r) vacc[r] = fmaf(coef, val[r], vacc[r]);
    }

    __shared__ float vtmp[4][DD];
#pragma unroll
    for (int r = 0; r < 5; ++r) vtmp[wid][r * 64 + lane] = vacc[r];
    __syncthreads();
    for (int j = threadIdx.x; j < DD; j += 256) {
        unsafeAtomicAdd(&v[j], vtmp[0][j] + vtmp[1][j] + vtmp[2][j] + vtmp[3][j]);
    }
}

// ---------------------------------------------------------------------------
// Kernel 4: sim[s] = rw[s] * dot(means[s], v); block partial -> atomic total.
// ---------------------------------------------------------------------------
__global__ __launch_bounds__(256) void sim_kernel(
    const float* __restrict__ means,
    const float* __restrict__ rw,
    const float* __restrict__ v,
    float* __restrict__ sim_out,
    float* __restrict__ simtotal)      // pre-zeroed
{
    const int wid = threadIdx.x >> 6;
    const int lane = threadIdx.x & 63;
    const int seg0 = blockIdx.x * 64 + wid * 16;

    float vreg[5];
#pragma unroll
    for (int r = 0; r < 5; ++r) vreg[r] = v[r * 64 + lane];

    float lsum = 0.f;
    for (int i = 0; i < 16; ++i) {
        const int s = seg0 + i;
        const float* row = means + (size_t)s * DD;
        float dot = 0.f;
#pragma unroll
        for (int r = 0; r < 5; ++r) dot = fmaf(row[r * 64 + lane], vreg[r], dot);
#pragma unroll
        for (int off = 32; off > 0; off >>= 1) dot += __shfl_xor(dot, off, 64);
        const float sim = rw[s] * dot;
        if (lane == 0) {
            sim_out[s] = sim;
            lsum += sim;
        }
    }
    __shared__ float stmp[4];
    if (lane == 0) stmp[wid] = lsum;
    __syncthreads();
    if (threadIdx.x == 0)
        unsafeAtomicAdd(simtotal, stmp[0] + stmp[1] + stmp[2] + stmp[3]);
}

// ---------------------------------------------------------------------------
// Kernel 5: clean mask (vectorized single block)
// ---------------------------------------------------------------------------
__global__ __launch_bounds__(256) void clean_kernel(
    const float* __restrict__ sim,
    const float* __restrict__ cls,
    const float* __restrict__ simtotal,
    const float* __restrict__ nvalid,
    float* __restrict__ clean_out)
{
    const float mean = simtotal[0] / fmaxf(nvalid[0], 1.f);
    const int tid = threadIdx.x;
    for (int i = tid; i < SS / 4; i += 256) {
        const float4 s4 = ((const float4*)sim)[i];
        const float4 c4 = ((const float4*)cls)[i];
        float4 o;
        o.x = (s4.x > mean && c4.x != 0.f) ? 1.f : 0.f;
        o.y = (s4.y > mean && c4.y != 0.f) ? 1.f : 0.f;
        o.z = (s4.z > mean && c4.z != 0.f) ? 1.f : 0.f;
        o.w = (s4.w > mean && c4.w != 0.f) ? 1.f : 0.f;
        ((float4*)clean_out)[i] = o;
    }
}

extern "C" void kernel_launch(void* const* d_in, const int* in_sizes, int n_in,
                              void* d_out, int out_size, void* d_ws, size_t ws_size,
                              hipStream_t stream) {
    const float* feat  = (const float*)d_in[0];
    const float* label = (const float*)d_in[1];
    const int*   clab  = (const int*)d_in[2];

    float* out       = (float*)d_out;
    float* means_out = out;
    float* sim_out   = out + (size_t)SS * DD;
    float* clean_out = sim_out + SS;

    // workspace layout (floats)
    float* ws = (float*)d_ws;
    unsigned* maxbits = (unsigned*)&ws[0];
    float* nvalid     = &ws[1];
    float* simtotal   = &ws[2];
    float* v          = &ws[4];                 // 320
    float* cls        = &ws[352];               // 8192
    float* sizes      = &ws[352 + SS];          // 8192
    float* rw         = &ws[352 + 2 * SS];      // 8192
    int*   starts     = (int*)&ws[352 + 3 * SS];            // 64*129
    unsigned short* spos = (unsigned short*)&ws[352 + 3 * SS + KC * (MC + 1)]; // 64*2048 u16

    // zero atomic targets (maxbits, nvalid, simtotal, v)
    hipMemsetAsync(d_ws, 0, 324 * sizeof(float), stream);

    sortstats_kernel<<<KC, 256, 0, stream>>>(label, clab, spos, starts,
                                             cls, sizes, maxbits, nvalid);
    means_kernel<<<dim3(KC, NCHUNKF), 512, 0, stream>>>(feat, spos, starts, means_out);
    norm_v_kernel<<<128, 256, 0, stream>>>(means_out, cls, sizes, maxbits, rw, v);
    sim_kernel<<<128, 256, 0, stream>>>(means_out, rw, v, sim_out, simtotal);
    clean_kernel<<<1, 256, 0, stream>>>(sim_out, cls, simtotal, nvalid, clean_out);
}